// Round 4
// baseline (102.026 us; speedup 1.0000x reference)
//
#include <hip/hip_runtime.h>
#include <math.h>

#define LOG2E 1.44269504088896340736f
#define LN2   0.69314718055994530942f

typedef _Float16 half8 __attribute__((ext_vector_type(8)));
typedef float f32x4v __attribute__((ext_vector_type(4)));

#define AROW 24   // halves per LDS row (48B): 16B-aligned frag reads

// ---------------------------------------------------------------------------
// kA: Lout[fb][b][g] = sum_{f in 128-range} exp( dot16(A[:,f], T[:,g]) )
// via mfma_f32_16x16x32_f16 with [Ah|Al] x [Th|Th] + [Ah|Al] x [Tl|0].
// v4: ONE 128-f tile per block, ONE barrier per block (no chunk loop, no
// convoy of 8 barriers). grid linear 8192 blocks (b=lin&31, fb=(lin>>5)&15,
// gb=lin>>9), block 256 (4 waves; wave owns 32 g-cols). 12KB LDS, VGPR~64
// -> 8 blocks/CU resident: one block's barrier/prologue overlaps seven
// others' MFMA+exp (block-level pipelining instead of intra-block chunks).
// ---------------------------------------------------------------------------
template <bool ATOMIC>
__global__ __launch_bounds__(256, 4) void kA(const float* __restrict__ data,
                                             const float* __restrict__ attn,
                                             float* __restrict__ Lout) {
    __shared__ _Float16 AhB[128 * AROW];
    __shared__ _Float16 AlB[128 * AROW];
    const int tid = threadIdx.x;
    const int lin = blockIdx.x;
    const int b = lin & 31, fb = (lin >> 5) & 15, gb = lin >> 9;
    const int wave = tid >> 6, lane = tid & 63;
    const int n = lane & 15, q = lane >> 4;
    const int s0 = (q & 1) * 8;

    // issue A-tile loads first (8 f32/thread, coalesced over f)
    const float* Ab = data + (size_t)b * 16 * 2048 + fb * 128;
    const int fst = tid & 127;       // f-row within tile (wave-consecutive)
    const int sh  = (tid >> 7) * 8;  // s-half
    float x[8];
#pragma unroll
    for (int j = 0; j < 8; ++j) x[j] = Ab[(size_t)(sh + j) * 2048 + fst];

    // B fragments (L2-resident: 16 fb-blocks share them). B[k=q*8+j][n].
    const float* Tb = attn + (size_t)b * 16 * 2048;
    half8 B1[2], B2[2];
#pragma unroll
    for (int ct = 0; ct < 2; ++ct) {
        const int g = gb * 128 + wave * 32 + ct * 16 + n;
        half8 bh, bl;
#pragma unroll
        for (int j = 0; j < 8; ++j) {
            float v = Tb[(size_t)(s0 + j) * 2048 + g] * LOG2E;
            _Float16 h = (_Float16)v;
            _Float16 l = (_Float16)(v - (float)h);
            bh[j] = h;
            bl[j] = (q < 2) ? l : (_Float16)0.0f;
        }
        B1[ct] = bh;
        B2[ct] = bl;
    }

    // stage A-tile (hi/lo split) into LDS; single barrier
    {
        half8 hv, lv;
#pragma unroll
        for (int j = 0; j < 8; ++j) {
            float v = x[j];
            _Float16 h = (_Float16)v;
            hv[j] = h;
            lv[j] = (_Float16)(v - (float)h);
        }
        *(half8*)(AhB + fst * AROW + sh) = hv;
        *(half8*)(AlB + fst * AROW + sh) = lv;
    }
    __syncthreads();

    f32x4v cs0 = {0.f, 0.f, 0.f, 0.f}, cs1 = {0.f, 0.f, 0.f, 0.f};
    const _Float16* aptr = ((q < 2) ? AhB : AlB) + n * AROW + s0;

#pragma unroll
    for (int rt = 0; rt < 8; ++rt) {
        half8 af = *(const half8*)(aptr + rt * 16 * AROW);
        f32x4v C = {0.f, 0.f, 0.f, 0.f};
        C = __builtin_amdgcn_mfma_f32_16x16x32_f16(af, B1[0], C, 0, 0, 0);
        C = __builtin_amdgcn_mfma_f32_16x16x32_f16(af, B2[0], C, 0, 0, 0);
        cs0[0] += __builtin_amdgcn_exp2f(C[0]);
        cs0[1] += __builtin_amdgcn_exp2f(C[1]);
        cs0[2] += __builtin_amdgcn_exp2f(C[2]);
        cs0[3] += __builtin_amdgcn_exp2f(C[3]);
        f32x4v D = {0.f, 0.f, 0.f, 0.f};
        D = __builtin_amdgcn_mfma_f32_16x16x32_f16(af, B1[1], D, 0, 0, 0);
        D = __builtin_amdgcn_mfma_f32_16x16x32_f16(af, B2[1], D, 0, 0, 0);
        cs1[0] += __builtin_amdgcn_exp2f(D[0]);
        cs1[1] += __builtin_amdgcn_exp2f(D[1]);
        cs1[2] += __builtin_amdgcn_exp2f(D[2]);
        cs1[3] += __builtin_amdgcn_exp2f(D[3]);
    }

    float v0 = cs0[0] + cs0[1] + cs0[2] + cs0[3];
    float v1 = cs1[0] + cs1[1] + cs1[2] + cs1[3];
    v0 += __shfl_xor(v0, 16);
    v0 += __shfl_xor(v0, 32);
    v1 += __shfl_xor(v1, 16);
    v1 += __shfl_xor(v1, 32);
    if (q == 0) {
        const int g = gb * 128 + wave * 32 + n;
        if (ATOMIC) {
            atomicAdd(&Lout[(size_t)b * 2048 + g], v0);
            atomicAdd(&Lout[(size_t)b * 2048 + g + 16], v1);
        } else {
            Lout[((size_t)fb * 32 + b) * 2048 + g] = v0;
            Lout[((size_t)fb * 32 + b) * 2048 + g + 16] = v1;
        }
    }
}

// ---------------------------------------------------------------------------
// kTail: per (128-g segment, b): L = ln2*log2(sum Lpart), c-partials, M-partials.
// grid (16, 32) = 512 blocks -> 2 blocks/CU.
// ---------------------------------------------------------------------------
#define TP2 132
__global__ __launch_bounds__(256) void kTail(const float* __restrict__ attn,
                                             const float* __restrict__ Lpart, int nparts,
                                             float* __restrict__ Mpart,
                                             float* __restrict__ cpart) {
    __shared__ float Tsh[16 * TP2];  // 8.4 KB
    __shared__ float Lsh[128];
    __shared__ float red[16][17];
    const int tid = threadIdx.x;
    const int seg = blockIdx.x, b = blockIdx.y;
    const int g0 = seg * 128;

    {
        const int gcol = tid & 127, sh = (tid >> 7) * 8;
#pragma unroll
        for (int j = 0; j < 8; ++j) {
            const int s = sh + j;
            Tsh[s * TP2 + gcol] = attn[(size_t)(b * 16 + s) * 2048 + g0 + gcol];
        }
    }
    if (tid < 128) {
        float sum = 0.f;
        for (int p = 0; p < nparts; ++p)
            sum += Lpart[((size_t)p * 32 + b) * 2048 + g0 + tid];
        Lsh[tid] = LN2 * __builtin_amdgcn_logf(sum);
    }
    __syncthreads();

    // c-partial: c[b][t] = sum_g Lsh[g]*Tsh[t][g]; t = tid&15, i-group of 8 g
    {
        const int t = tid & 15, i = tid >> 4;
        float acc = 0.f;
#pragma unroll
        for (int k = 0; k < 2; ++k) {
            float4 l  = *(const float4*)(Lsh + i * 8 + k * 4);
            float4 tv = *(const float4*)(Tsh + t * TP2 + i * 8 + k * 4);
            acc += l.x * tv.x + l.y * tv.y + l.z * tv.z + l.w * tv.w;
        }
        red[t][i] = acc;
    }
    __syncthreads();
    if (tid < 16) {
        float s = 0.f;
#pragma unroll
        for (int k = 0; k < 16; ++k) s += red[tid][k];
        cpart[((size_t)seg * 32 + b) * 16 + tid] = s;
    }

    // M-partial: M[b][s][t] = sum_g Tsh[s][g]*Tsh[t][g]; thread = (s,t)
    {
        const int s = tid >> 4, t = tid & 15;
        float a0 = 0.f, a1 = 0.f;
#pragma unroll 4
        for (int qk = 0; qk < 16; ++qk) {
            float4 xv = *(const float4*)(Tsh + s * TP2 + qk * 8);
            float4 yv = *(const float4*)(Tsh + t * TP2 + qk * 8);
            a0 += xv.x * yv.x + xv.y * yv.y + xv.z * yv.z + xv.w * yv.w;
            float4 x2 = *(const float4*)(Tsh + s * TP2 + qk * 8 + 4);
            float4 y2 = *(const float4*)(Tsh + t * TP2 + qk * 8 + 4);
            a1 += x2.x * y2.x + x2.y * y2.y + x2.z * y2.z + x2.w * y2.w;
        }
        Mpart[((size_t)seg * 32 + b) * 256 + tid] = a0 + a1;
    }
}

// ---------------------------------------------------------------------------
// kC2: fold M/c partials with W,bias (redundant per block, cheap) + epilogue.
// grid (16, 32) = 512 blocks -> 2 blocks/CU; 128 f per block, 2 j-halves.
// ---------------------------------------------------------------------------
#define NSEG 16
__global__ __launch_bounds__(256) void kC2(const float* __restrict__ data,
                                           const float* __restrict__ Mpart,
                                           const float* __restrict__ cpart,
                                           const float* __restrict__ W,
                                           const float* __restrict__ bias,
                                           float* __restrict__ out) {
    __shared__ float Msh[256];
    __shared__ float csh[16];
    __shared__ float Vsh[256];
    __shared__ float w0sh[16];
    const int tid = threadIdx.x;
    const int b = blockIdx.y;
    const int f = blockIdx.x * 128 + (tid & 127);
    const int jh = tid >> 7;

    {
        float m = 0.f;
#pragma unroll
        for (int p = 0; p < NSEG; ++p) m += Mpart[((size_t)p * 32 + b) * 256 + tid];
        Msh[tid] = m;
        if (tid < 16) {
            float c = 0.f;
#pragma unroll
            for (int p = 0; p < NSEG; ++p) c += cpart[((size_t)p * 32 + b) * 16 + tid];
            csh[tid] = c;
        }
    }
    __syncthreads();
    {
        const int s = tid >> 4, j = tid & 15;
        float acc = 0.f;
#pragma unroll
        for (int t = 0; t < 16; ++t) acc += Msh[s * 16 + t] * W[j * 32 + t];
        Vsh[s * 16 + j] = acc + W[j * 32 + 16 + s];
        if (s == 0) {
            float w0 = 0.f;
#pragma unroll
            for (int t = 0; t < 16; ++t) w0 += csh[t] * W[j * 32 + t];
            w0sh[j] = bias[j] - w0;
        }
    }
    __syncthreads();

    float As[16];
#pragma unroll
    for (int s = 0; s < 16; ++s)
        As[s] = data[(size_t)(b * 16 + s) * 2048 + f];
#pragma unroll
    for (int jj = 0; jj < 8; ++jj) {
        const int j = jh * 8 + jj;
        float p = w0sh[j];
#pragma unroll
        for (int s = 0; s < 16; ++s) p += As[s] * Vsh[s * 16 + j];
        float e = __builtin_amdgcn_exp2f(-LOG2E * p);
        float gate = __builtin_amdgcn_rcpf(1.0f + e);
        size_t r = (size_t)(j * 32 + b) * 2048 + f;
        out[r] = gate * data[r];
    }
}

extern "C" void kernel_launch(void* const* d_in, const int* in_sizes, int n_in,
                              void* d_out, int out_size, void* d_ws, size_t ws_size,
                              hipStream_t stream) {
    const float* data = (const float*)d_in[0];
    const float* attn = (const float*)d_in[1];
    const float* W    = (const float*)d_in[2];
    const float* bias = (const float*)d_in[3];
    float* out = (float*)d_out;
    float* ws  = (float*)d_ws;

    // big layout: Lpart[16][32][2048] | Mpart[16][32][256] | cpart[16][32][16]
    const size_t LP = 16 * 32 * 2048;             // 1048576
    const size_t MP = NSEG * 32 * 256;            // 131072
    const size_t CP = NSEG * 32 * 16;             // 8192
    const size_t need_big = LP + MP + CP;

    if (ws_size >= need_big * sizeof(float)) {
        float* Lpart = ws;
        float* Mpart = ws + LP;
        float* cpart = Mpart + MP;
        kA<false><<<dim3(8192, 1, 1), 256, 0, stream>>>(data, attn, Lpart);
        kTail<<<dim3(16, 32), 256, 0, stream>>>(attn, Lpart, 16, Mpart, cpart);
        kC2<<<dim3(16, 32), 256, 0, stream>>>(data, Mpart, cpart, W, bias, out);
    } else {
        float* Lsum  = ws;            // 65536
        float* Mpart = ws + 65536;
        float* cpart = Mpart + MP;
        hipMemsetAsync(Lsum, 0, 65536 * sizeof(float), stream);
        kA<true><<<dim3(8192, 1, 1), 256, 0, stream>>>(data, attn, Lsum);
        kTail<<<dim3(16, 32), 256, 0, stream>>>(attn, Lsum, 1, Mpart, cpart);
        kC2<<<dim3(16, 32), 256, 0, stream>>>(data, Mpart, cpart, W, bias, out);
    }
}

// Round 5
// 101.430 us; speedup vs baseline: 1.0059x; 1.0059x over previous
//
#include <hip/hip_runtime.h>
#include <math.h>

#define LOG2E 1.44269504088896340736f
#define LN2   0.69314718055994530942f

typedef _Float16 half8 __attribute__((ext_vector_type(8)));
typedef float f32x4v __attribute__((ext_vector_type(4)));

#define AROW 24   // halves per LDS row (48B): 16B-aligned frag reads

// VALU polynomial exp2: rndne + sub + 4*fma + cvt + ldexp = ~8 VALU instrs.
// Runs on the main SIMD pipe, NOT the transcendental pipe -> relieves trans
// throughput if kA is trans-bound. |rel err| ~4e-5 on r in [-0.5,0.5].
__device__ __forceinline__ float exp2_poly(float x) {
    float n = rintf(x);                      // v_rndne_f32
    float r = x - n;                         // r in [-0.5, 0.5]
    float p = fmaf(r, 0.0096181291f, 0.0555041086f);
    p = fmaf(r, p, 0.2402265069f);
    p = fmaf(r, p, 0.6931471806f);
    p = fmaf(r, p, 1.0f);
    return __builtin_amdgcn_ldexpf(p, (int)n);  // v_ldexp_f32
}

// ---------------------------------------------------------------------------
// kA: Lout[fb][b][g] = sum_{f in 512-range} exp( dot16(A[:,f], T[:,g]) )
// via mfma_f32_16x16x32_f16 with [Ah|Al] x [Th|Th] + [Ah|Al] x [Tl|0].
// grid linear 2048 blocks, decode b=x&31, fb=(x>>5)&3, gb=x>>7.
// block 256 (4 waves; wave owns 32 g-cols). 8 blocks/CU, VGPR~64, 12KB LDS
// -> full residency. r5 delta: HYBRID exp — cs0 side on the trans pipe
// (v_exp_f32), cs1 side on the VALU (poly). If kA was trans-throughput-
// bound at ~27us, halving trans load should drop it to max(trans,VALU)~14us.
// ---------------------------------------------------------------------------
template <bool ATOMIC>
__global__ __launch_bounds__(256, 4) void kA(const float* __restrict__ data,
                                             const float* __restrict__ attn,
                                             float* __restrict__ Lout) {
    __shared__ _Float16 AhB[128 * AROW];
    __shared__ _Float16 AlB[128 * AROW];
    const int tid = threadIdx.x;
    const int lin = blockIdx.x;
    const int b = lin & 31, fb = (lin >> 5) & 3, gb = lin >> 7;
    const int wave = tid >> 6, lane = tid & 63;
    const int n = lane & 15, q = lane >> 4;
    const int s0 = (q & 1) * 8;

    // B fragments (loop-invariant). B[k=q*8+j][n]; k mod 16 = s0+j.
    const float* Tb = attn + (size_t)b * 16 * 2048;
    half8 B1[2], B2[2];
#pragma unroll
    for (int ct = 0; ct < 2; ++ct) {
        const int g = gb * 128 + wave * 32 + ct * 16 + n;
        half8 bh, bl;
#pragma unroll
        for (int j = 0; j < 8; ++j) {
            float x = Tb[(size_t)(s0 + j) * 2048 + g] * LOG2E;
            _Float16 h = (_Float16)x;
            _Float16 l = (_Float16)(x - (float)h);
            bh[j] = h;
            bl[j] = (q < 2) ? l : (_Float16)0.0f;
        }
        B1[ct] = bh;
        B2[ct] = bl;
    }

    f32x4v cs0 = {0.f, 0.f, 0.f, 0.f}, cs1 = {0.f, 0.f, 0.f, 0.f};

    const float* Ab = data + (size_t)b * 16 * 2048 + fb * 512;
    const int fst = tid & 127;       // f-row within tile (wave-consecutive)
    const int sh  = (tid >> 7) * 8;  // s-half
    const _Float16* aptr = ((q < 2) ? AhB : AlB) + n * AROW + s0;

    // prologue: issue chunk 0's loads
    float x[8];
#pragma unroll
    for (int j = 0; j < 8; ++j) x[j] = Ab[(size_t)(sh + j) * 2048 + fst];

    for (int chunk = 0; chunk < 4; ++chunk) {
        // convert staged chunk (loads were issued one compute-phase ago)
        half8 hv, lv;
#pragma unroll
        for (int j = 0; j < 8; ++j) {
            float v = x[j];
            _Float16 h = (_Float16)v;
            hv[j] = h;
            lv[j] = (_Float16)(v - (float)h);
        }
        __syncthreads();  // previous chunk's compute done reading LDS
        *(half8*)(AhB + fst * AROW + sh) = hv;
        *(half8*)(AlB + fst * AROW + sh) = lv;
        __syncthreads();

        // issue next chunk's loads; they fly under the MFMA+exp below
        if (chunk < 3) {
            const float* Ac = Ab + (chunk + 1) * 128;
#pragma unroll
            for (int j = 0; j < 8; ++j) x[j] = Ac[(size_t)(sh + j) * 2048 + fst];
        }

#pragma unroll
        for (int rt = 0; rt < 8; ++rt) {
            half8 af = *(const half8*)(aptr + rt * 16 * AROW);
            f32x4v C = {0.f, 0.f, 0.f, 0.f};
            C = __builtin_amdgcn_mfma_f32_16x16x32_f16(af, B1[0], C, 0, 0, 0);
            C = __builtin_amdgcn_mfma_f32_16x16x32_f16(af, B2[0], C, 0, 0, 0);
            // trans-pipe side
            cs0[0] += __builtin_amdgcn_exp2f(C[0]);
            cs0[1] += __builtin_amdgcn_exp2f(C[1]);
            cs0[2] += __builtin_amdgcn_exp2f(C[2]);
            cs0[3] += __builtin_amdgcn_exp2f(C[3]);
            f32x4v D = {0.f, 0.f, 0.f, 0.f};
            D = __builtin_amdgcn_mfma_f32_16x16x32_f16(af, B1[1], D, 0, 0, 0);
            D = __builtin_amdgcn_mfma_f32_16x16x32_f16(af, B2[1], D, 0, 0, 0);
            // VALU-poly side (overlaps the trans work above)
            cs1[0] += exp2_poly(D[0]);
            cs1[1] += exp2_poly(D[1]);
            cs1[2] += exp2_poly(D[2]);
            cs1[3] += exp2_poly(D[3]);
        }
    }

    float v0 = cs0[0] + cs0[1] + cs0[2] + cs0[3];
    float v1 = cs1[0] + cs1[1] + cs1[2] + cs1[3];
    v0 += __shfl_xor(v0, 16);
    v0 += __shfl_xor(v0, 32);
    v1 += __shfl_xor(v1, 16);
    v1 += __shfl_xor(v1, 32);
    if (q == 0) {
        const int g = gb * 128 + wave * 32 + n;
        if (ATOMIC) {
            atomicAdd(&Lout[(size_t)b * 2048 + g], v0);
            atomicAdd(&Lout[(size_t)b * 2048 + g + 16], v1);
        } else {
            Lout[((size_t)fb * 32 + b) * 2048 + g] = v0;
            Lout[((size_t)fb * 32 + b) * 2048 + g + 16] = v1;
        }
    }
}

// ---------------------------------------------------------------------------
// kTail: per (128-g segment, b): L = ln2*log2(sum Lpart), c-partials, M-partials.
// grid (16, 32) = 512 blocks -> 2 blocks/CU.
// ---------------------------------------------------------------------------
#define TP2 132
__global__ __launch_bounds__(256) void kTail(const float* __restrict__ attn,
                                             const float* __restrict__ Lpart, int nparts,
                                             float* __restrict__ Mpart,
                                             float* __restrict__ cpart) {
    __shared__ float Tsh[16 * TP2];  // 8.4 KB
    __shared__ float Lsh[128];
    __shared__ float red[16][17];
    const int tid = threadIdx.x;
    const int seg = blockIdx.x, b = blockIdx.y;
    const int g0 = seg * 128;

    {
        const int gcol = tid & 127, sh = (tid >> 7) * 8;
#pragma unroll
        for (int j = 0; j < 8; ++j) {
            const int s = sh + j;
            Tsh[s * TP2 + gcol] = attn[(size_t)(b * 16 + s) * 2048 + g0 + gcol];
        }
    }
    if (tid < 128) {
        float sum = 0.f;
        for (int p = 0; p < nparts; ++p)
            sum += Lpart[((size_t)p * 32 + b) * 2048 + g0 + tid];
        Lsh[tid] = LN2 * __builtin_amdgcn_logf(sum);
    }
    __syncthreads();

    // c-partial: c[b][t] = sum_g Lsh[g]*Tsh[t][g]; t = tid&15, i-group of 8 g
    {
        const int t = tid & 15, i = tid >> 4;
        float acc = 0.f;
#pragma unroll
        for (int k = 0; k < 2; ++k) {
            float4 l  = *(const float4*)(Lsh + i * 8 + k * 4);
            float4 tv = *(const float4*)(Tsh + t * TP2 + i * 8 + k * 4);
            acc += l.x * tv.x + l.y * tv.y + l.z * tv.z + l.w * tv.w;
        }
        red[t][i] = acc;
    }
    __syncthreads();
    if (tid < 16) {
        float s = 0.f;
#pragma unroll
        for (int k = 0; k < 16; ++k) s += red[tid][k];
        cpart[((size_t)seg * 32 + b) * 16 + tid] = s;
    }

    // M-partial: M[b][s][t] = sum_g Tsh[s][g]*Tsh[t][g]; thread = (s,t)
    {
        const int s = tid >> 4, t = tid & 15;
        float a0 = 0.f, a1 = 0.f;
#pragma unroll 4
        for (int qk = 0; qk < 16; ++qk) {
            float4 xv = *(const float4*)(Tsh + s * TP2 + qk * 8);
            float4 yv = *(const float4*)(Tsh + t * TP2 + qk * 8);
            a0 += xv.x * yv.x + xv.y * yv.y + xv.z * yv.z + xv.w * yv.w;
            float4 x2 = *(const float4*)(Tsh + s * TP2 + qk * 8 + 4);
            float4 y2 = *(const float4*)(Tsh + t * TP2 + qk * 8 + 4);
            a1 += x2.x * y2.x + x2.y * y2.y + x2.z * y2.z + x2.w * y2.w;
        }
        Mpart[((size_t)seg * 32 + b) * 256 + tid] = a0 + a1;
    }
}

// ---------------------------------------------------------------------------
// kC2: fold M/c partials with W,bias (redundant per block, cheap) + epilogue.
// grid (16, 32) = 512 blocks -> 2 blocks/CU; 128 f per block, 2 j-halves.
// ---------------------------------------------------------------------------
#define NSEG 16
__global__ __launch_bounds__(256) void kC2(const float* __restrict__ data,
                                           const float* __restrict__ Mpart,
                                           const float* __restrict__ cpart,
                                           const float* __restrict__ W,
                                           const float* __restrict__ bias,
                                           float* __restrict__ out) {
    __shared__ float Msh[256];
    __shared__ float csh[16];
    __shared__ float Vsh[256];
    __shared__ float w0sh[16];
    const int tid = threadIdx.x;
    const int b = blockIdx.y;
    const int f = blockIdx.x * 128 + (tid & 127);
    const int jh = tid >> 7;

    {
        float m = 0.f;
#pragma unroll
        for (int p = 0; p < NSEG; ++p) m += Mpart[((size_t)p * 32 + b) * 256 + tid];
        Msh[tid] = m;
        if (tid < 16) {
            float c = 0.f;
#pragma unroll
            for (int p = 0; p < NSEG; ++p) c += cpart[((size_t)p * 32 + b) * 16 + tid];
            csh[tid] = c;
        }
    }
    __syncthreads();
    {
        const int s = tid >> 4, j = tid & 15;
        float acc = 0.f;
#pragma unroll
        for (int t = 0; t < 16; ++t) acc += Msh[s * 16 + t] * W[j * 32 + t];
        Vsh[s * 16 + j] = acc + W[j * 32 + 16 + s];
        if (s == 0) {
            float w0 = 0.f;
#pragma unroll
            for (int t = 0; t < 16; ++t) w0 += csh[t] * W[j * 32 + t];
            w0sh[j] = bias[j] - w0;
        }
    }
    __syncthreads();

    float As[16];
#pragma unroll
    for (int s = 0; s < 16; ++s)
        As[s] = data[(size_t)(b * 16 + s) * 2048 + f];
#pragma unroll
    for (int jj = 0; jj < 8; ++jj) {
        const int j = jh * 8 + jj;
        float p = w0sh[j];
#pragma unroll
        for (int s = 0; s < 16; ++s) p += As[s] * Vsh[s * 16 + j];
        float e = __builtin_amdgcn_exp2f(-LOG2E * p);
        float gate = __builtin_amdgcn_rcpf(1.0f + e);
        size_t r = (size_t)(j * 32 + b) * 2048 + f;
        out[r] = gate * data[r];
    }
}

extern "C" void kernel_launch(void* const* d_in, const int* in_sizes, int n_in,
                              void* d_out, int out_size, void* d_ws, size_t ws_size,
                              hipStream_t stream) {
    const float* data = (const float*)d_in[0];
    const float* attn = (const float*)d_in[1];
    const float* W    = (const float*)d_in[2];
    const float* bias = (const float*)d_in[3];
    float* out = (float*)d_out;
    float* ws  = (float*)d_ws;

    // big layout: Lpart[4][32][2048] | Mpart[16][32][256] | cpart[16][32][16]
    const size_t LP = 4 * 32 * 2048;              // 262144
    const size_t MP = NSEG * 32 * 256;            // 131072
    const size_t CP = NSEG * 32 * 16;             // 8192
    const size_t need_big = LP + MP + CP;

    if (ws_size >= need_big * sizeof(float)) {
        float* Lpart = ws;
        float* Mpart = ws + LP;
        float* cpart = Mpart + MP;
        kA<false><<<dim3(2048, 1, 1), 256, 0, stream>>>(data, attn, Lpart);
        kTail<<<dim3(16, 32), 256, 0, stream>>>(attn, Lpart, 4, Mpart, cpart);
        kC2<<<dim3(16, 32), 256, 0, stream>>>(data, Mpart, cpart, W, bias, out);
    } else {
        float* Lsum  = ws;            // 65536
        float* Mpart = ws + 65536;
        float* cpart = Mpart + MP;
        hipMemsetAsync(Lsum, 0, 65536 * sizeof(float), stream);
        kA<true><<<dim3(2048, 1, 1), 256, 0, stream>>>(data, attn, Lsum);
        kTail<<<dim3(16, 32), 256, 0, stream>>>(attn, Lsum, 1, Mpart, cpart);
        kC2<<<dim3(16, 32), 256, 0, stream>>>(data, Mpart, cpart, W, bias, out);
    }
}

// Round 6
// 96.376 us; speedup vs baseline: 1.0586x; 1.0524x over previous
//
#include <hip/hip_runtime.h>
#include <math.h>

#define LOG2E 1.44269504088896340736f
#define LN2   0.69314718055994530942f

typedef _Float16 half8 __attribute__((ext_vector_type(8)));
typedef float f32x4v __attribute__((ext_vector_type(4)));

// ---------------------------------------------------------------------------
// kPrep: one-time conversion of data/attn into MFMA fragment images.
// Afrag[(b*4+fb)*32 + rr][q][n] : half8 = A_{hi if q<2 else lo}[s=(q&1)*8+j][f]
//   with f = fb*512 + rr*16 + n  (rr = c*8+rt, 1KB per fragment)
// Tfrag[b][p][g] : half8 = T_{hi if p<2 else lo}[s=(p&1)*8+j][g] * LOG2E
// This hoists the hi/lo cvt work that kA previously repeated per gb-block
// (x16 for data, x4 for attn) and lets kA read fragments as single
// coalesced 16B global loads (no LDS, no barriers).
// grid (8, 32), block 256. ~32MB traffic => ~5us.
// ---------------------------------------------------------------------------
__global__ __launch_bounds__(256) void kPrep(const float* __restrict__ data,
                                             const float* __restrict__ attn,
                                             _Float16* __restrict__ Afrag,
                                             _Float16* __restrict__ Tfrag) {
    const int tid = threadIdx.x;
    const int b = blockIdx.y;
    const int f = blockIdx.x * 256 + tid;

    // data -> Afrag (hi/lo split, unscaled)
    _Float16 h16[16], l16[16];
#pragma unroll
    for (int s = 0; s < 16; ++s) {
        float v = data[(size_t)(b * 16 + s) * 2048 + f];
        _Float16 h = (_Float16)v;
        h16[s] = h;
        l16[s] = (_Float16)(v - (float)h);
    }
    {
        const int fb = f >> 9, c = (f >> 7) & 3, rt = (f >> 4) & 7, n = f & 15;
        _Float16* dst = Afrag + ((size_t)((b * 4 + fb) * 32 + c * 8 + rt)) * 512 + n * 8;
#pragma unroll
        for (int qq = 0; qq < 4; ++qq) {
            const _Float16* src = (qq < 2) ? h16 : l16;
            const int s0 = (qq & 1) * 8;
            half8 v;
#pragma unroll
            for (int j = 0; j < 8; ++j) v[j] = src[s0 + j];
            *(half8*)(dst + qq * 128) = v;
        }
    }

    // attn -> Tfrag (prescaled by LOG2E, hi/lo split)
    _Float16 th[16], tl[16];
#pragma unroll
    for (int s = 0; s < 16; ++s) {
        float v = attn[(size_t)(b * 16 + s) * 2048 + f] * LOG2E;
        _Float16 h = (_Float16)v;
        th[s] = h;
        tl[s] = (_Float16)(v - (float)h);
    }
#pragma unroll
    for (int p = 0; p < 4; ++p) {
        const _Float16* src = (p < 2) ? th : tl;
        const int s0 = (p & 1) * 8;
        half8 v;
#pragma unroll
        for (int j = 0; j < 8; ++j) v[j] = src[s0 + j];
        *(half8*)(Tfrag + ((size_t)(b * 4 + p) * 2048 + f) * 8) = v;
    }
}

// ---------------------------------------------------------------------------
// kA v6: Lout[fb][b][g] = sum_{f in 512-range} exp2( dot16hl(A[:,f], T[:,g]) )
// NO LDS, NO barriers, NO cvt: fragments read directly from the kPrep images.
// Inner loop per rr: 1 global_load_dwordx4 (L1/L2-hit) + 4 MFMA + 8 exp + 8 add.
// grid linear 2048 (gb=lin&15 so the 16 sharers of one (b,fb) image are
// dispatch-adjacent), block 256 = 4 waves; 8 blocks/CU at VGPR<=64..128.
// ---------------------------------------------------------------------------
template <bool ATOMIC>
__global__ __launch_bounds__(256, 4) void kA(const _Float16* __restrict__ Afrag,
                                             const _Float16* __restrict__ Tfrag,
                                             float* __restrict__ Lout) {
    const int tid = threadIdx.x;
    const int lin = blockIdx.x;
    const int gb = lin & 15, b = (lin >> 4) & 31, fb = lin >> 9;
    const int wave = tid >> 6, lane = tid & 63;
    const int n = lane & 15, q = lane >> 4;

    // B fragments: direct 16B loads. B1 = Thi at s-half (q&1) for all q;
    // B2 = Tlo for q<2, zero for q>=2 (hi/lo compensation: (Ah+Al)Th + Ah*Tl).
    half8 B1[2], B2[2];
    const half8 zero = {};
#pragma unroll
    for (int ct = 0; ct < 2; ++ct) {
        const int g = gb * 128 + wave * 32 + ct * 16 + n;
        B1[ct] = *(const half8*)(Tfrag + ((size_t)(b * 4 + (q & 1)) * 2048 + g) * 8);
        half8 b2 = *(const half8*)(Tfrag + ((size_t)(b * 4 + 2 + (q & 1)) * 2048 + g) * 8);
        B2[ct] = (q < 2) ? b2 : zero;
    }

    f32x4v cs0 = {0.f, 0.f, 0.f, 0.f}, cs1 = {0.f, 0.f, 0.f, 0.f};
    // A-fragment stream: lane l = q*16+n reads bytes l*16 of each 1KB fragment.
    const _Float16* Ab = Afrag + ((size_t)((b * 4 + fb) * 32)) * 512 + lane * 8;

#pragma unroll 4
    for (int rr = 0; rr < 32; ++rr) {
        half8 af = *(const half8*)(Ab + (size_t)rr * 512);
        f32x4v C = {0.f, 0.f, 0.f, 0.f};
        C = __builtin_amdgcn_mfma_f32_16x16x32_f16(af, B1[0], C, 0, 0, 0);
        C = __builtin_amdgcn_mfma_f32_16x16x32_f16(af, B2[0], C, 0, 0, 0);
        cs0[0] += __builtin_amdgcn_exp2f(C[0]);
        cs0[1] += __builtin_amdgcn_exp2f(C[1]);
        cs0[2] += __builtin_amdgcn_exp2f(C[2]);
        cs0[3] += __builtin_amdgcn_exp2f(C[3]);
        f32x4v D = {0.f, 0.f, 0.f, 0.f};
        D = __builtin_amdgcn_mfma_f32_16x16x32_f16(af, B1[1], D, 0, 0, 0);
        D = __builtin_amdgcn_mfma_f32_16x16x32_f16(af, B2[1], D, 0, 0, 0);
        cs1[0] += __builtin_amdgcn_exp2f(D[0]);
        cs1[1] += __builtin_amdgcn_exp2f(D[1]);
        cs1[2] += __builtin_amdgcn_exp2f(D[2]);
        cs1[3] += __builtin_amdgcn_exp2f(D[3]);
    }

    float v0 = cs0[0] + cs0[1] + cs0[2] + cs0[3];
    float v1 = cs1[0] + cs1[1] + cs1[2] + cs1[3];
    v0 += __shfl_xor(v0, 16);
    v0 += __shfl_xor(v0, 32);
    v1 += __shfl_xor(v1, 16);
    v1 += __shfl_xor(v1, 32);
    if (q == 0) {
        const int g = gb * 128 + wave * 32 + n;
        if (ATOMIC) {
            atomicAdd(&Lout[(size_t)b * 2048 + g], v0);
            atomicAdd(&Lout[(size_t)b * 2048 + g + 16], v1);
        } else {
            Lout[((size_t)fb * 32 + b) * 2048 + g] = v0;
            Lout[((size_t)fb * 32 + b) * 2048 + g + 16] = v1;
        }
    }
}

// ---------------------------------------------------------------------------
// kA_lds: the r3 LDS-staging variant, kept ONLY for the tiny-workspace
// fallback path (frag images need ~8MB of ws).
// ---------------------------------------------------------------------------
#define AROW 24
__global__ __launch_bounds__(256, 4) void kA_lds(const float* __restrict__ data,
                                                 const float* __restrict__ attn,
                                                 float* __restrict__ Lout) {
    __shared__ _Float16 AhB[128 * AROW];
    __shared__ _Float16 AlB[128 * AROW];
    const int tid = threadIdx.x;
    const int lin = blockIdx.x;
    const int b = lin & 31, fb = (lin >> 5) & 3, gb = lin >> 7;
    const int wave = tid >> 6, lane = tid & 63;
    const int n = lane & 15, q = lane >> 4;
    const int s0 = (q & 1) * 8;

    const float* Tb = attn + (size_t)b * 16 * 2048;
    half8 B1[2], B2[2];
#pragma unroll
    for (int ct = 0; ct < 2; ++ct) {
        const int g = gb * 128 + wave * 32 + ct * 16 + n;
        half8 bh, bl;
#pragma unroll
        for (int j = 0; j < 8; ++j) {
            float x = Tb[(size_t)(s0 + j) * 2048 + g] * LOG2E;
            _Float16 h = (_Float16)x;
            _Float16 l = (_Float16)(x - (float)h);
            bh[j] = h;
            bl[j] = (q < 2) ? l : (_Float16)0.0f;
        }
        B1[ct] = bh;
        B2[ct] = bl;
    }

    f32x4v cs0 = {0.f, 0.f, 0.f, 0.f}, cs1 = {0.f, 0.f, 0.f, 0.f};
    const float* Ab = data + (size_t)b * 16 * 2048 + fb * 512;
    const int fst = tid & 127;
    const int sh = (tid >> 7) * 8;
    const _Float16* aptr = ((q < 2) ? AhB : AlB) + n * AROW + s0;

    float x[8];
#pragma unroll
    for (int j = 0; j < 8; ++j) x[j] = Ab[(size_t)(sh + j) * 2048 + fst];

    for (int chunk = 0; chunk < 4; ++chunk) {
        half8 hv, lv;
#pragma unroll
        for (int j = 0; j < 8; ++j) {
            float v = x[j];
            _Float16 h = (_Float16)v;
            hv[j] = h;
            lv[j] = (_Float16)(v - (float)h);
        }
        __syncthreads();
        *(half8*)(AhB + fst * AROW + sh) = hv;
        *(half8*)(AlB + fst * AROW + sh) = lv;
        __syncthreads();
        if (chunk < 3) {
            const float* Ac = Ab + (chunk + 1) * 128;
#pragma unroll
            for (int j = 0; j < 8; ++j) x[j] = Ac[(size_t)(sh + j) * 2048 + fst];
        }
#pragma unroll
        for (int rt = 0; rt < 8; ++rt) {
            half8 af = *(const half8*)(aptr + rt * 16 * AROW);
            f32x4v C = {0.f, 0.f, 0.f, 0.f};
            C = __builtin_amdgcn_mfma_f32_16x16x32_f16(af, B1[0], C, 0, 0, 0);
            C = __builtin_amdgcn_mfma_f32_16x16x32_f16(af, B2[0], C, 0, 0, 0);
            cs0[0] += __builtin_amdgcn_exp2f(C[0]);
            cs0[1] += __builtin_amdgcn_exp2f(C[1]);
            cs0[2] += __builtin_amdgcn_exp2f(C[2]);
            cs0[3] += __builtin_amdgcn_exp2f(C[3]);
            f32x4v D = {0.f, 0.f, 0.f, 0.f};
            D = __builtin_amdgcn_mfma_f32_16x16x32_f16(af, B1[1], D, 0, 0, 0);
            D = __builtin_amdgcn_mfma_f32_16x16x32_f16(af, B2[1], D, 0, 0, 0);
            cs1[0] += __builtin_amdgcn_exp2f(D[0]);
            cs1[1] += __builtin_amdgcn_exp2f(D[1]);
            cs1[2] += __builtin_amdgcn_exp2f(D[2]);
            cs1[3] += __builtin_amdgcn_exp2f(D[3]);
        }
    }

    float v0 = cs0[0] + cs0[1] + cs0[2] + cs0[3];
    float v1 = cs1[0] + cs1[1] + cs1[2] + cs1[3];
    v0 += __shfl_xor(v0, 16);
    v0 += __shfl_xor(v0, 32);
    v1 += __shfl_xor(v1, 16);
    v1 += __shfl_xor(v1, 32);
    if (q == 0) {
        const int g = gb * 128 + wave * 32 + n;
        atomicAdd(&Lout[(size_t)b * 2048 + g], v0);
        atomicAdd(&Lout[(size_t)b * 2048 + g + 16], v1);
    }
}

// ---------------------------------------------------------------------------
// kTail: per (128-g segment, b): L = ln2*log2(sum Lpart), c-partials, M-partials.
// grid (16, 32) = 512 blocks -> 2 blocks/CU.
// ---------------------------------------------------------------------------
#define TP2 132
__global__ __launch_bounds__(256) void kTail(const float* __restrict__ attn,
                                             const float* __restrict__ Lpart, int nparts,
                                             float* __restrict__ Mpart,
                                             float* __restrict__ cpart) {
    __shared__ float Tsh[16 * TP2];  // 8.4 KB
    __shared__ float Lsh[128];
    __shared__ float red[16][17];
    const int tid = threadIdx.x;
    const int seg = blockIdx.x, b = blockIdx.y;
    const int g0 = seg * 128;

    {
        const int gcol = tid & 127, sh = (tid >> 7) * 8;
#pragma unroll
        for (int j = 0; j < 8; ++j) {
            const int s = sh + j;
            Tsh[s * TP2 + gcol] = attn[(size_t)(b * 16 + s) * 2048 + g0 + gcol];
        }
    }
    if (tid < 128) {
        float sum = 0.f;
        for (int p = 0; p < nparts; ++p)
            sum += Lpart[((size_t)p * 32 + b) * 2048 + g0 + tid];
        Lsh[tid] = LN2 * __builtin_amdgcn_logf(sum);
    }
    __syncthreads();

    {
        const int t = tid & 15, i = tid >> 4;
        float acc = 0.f;
#pragma unroll
        for (int k = 0; k < 2; ++k) {
            float4 l  = *(const float4*)(Lsh + i * 8 + k * 4);
            float4 tv = *(const float4*)(Tsh + t * TP2 + i * 8 + k * 4);
            acc += l.x * tv.x + l.y * tv.y + l.z * tv.z + l.w * tv.w;
        }
        red[t][i] = acc;
    }
    __syncthreads();
    if (tid < 16) {
        float s = 0.f;
#pragma unroll
        for (int k = 0; k < 16; ++k) s += red[tid][k];
        cpart[((size_t)seg * 32 + b) * 16 + tid] = s;
    }

    {
        const int s = tid >> 4, t = tid & 15;
        float a0 = 0.f, a1 = 0.f;
#pragma unroll 4
        for (int qk = 0; qk < 16; ++qk) {
            float4 xv = *(const float4*)(Tsh + s * TP2 + qk * 8);
            float4 yv = *(const float4*)(Tsh + t * TP2 + qk * 8);
            a0 += xv.x * yv.x + xv.y * yv.y + xv.z * yv.z + xv.w * yv.w;
            float4 x2 = *(const float4*)(Tsh + s * TP2 + qk * 8 + 4);
            float4 y2 = *(const float4*)(Tsh + t * TP2 + qk * 8 + 4);
            a1 += x2.x * y2.x + x2.y * y2.y + x2.z * y2.z + x2.w * y2.w;
        }
        Mpart[((size_t)seg * 32 + b) * 256 + tid] = a0 + a1;
    }
}

// ---------------------------------------------------------------------------
// kC2: fold M/c partials with W,bias (redundant per block, cheap) + epilogue.
// grid (16, 32) = 512 blocks -> 2 blocks/CU; 128 f per block, 2 j-halves.
// ---------------------------------------------------------------------------
#define NSEG 16
__global__ __launch_bounds__(256) void kC2(const float* __restrict__ data,
                                           const float* __restrict__ Mpart,
                                           const float* __restrict__ cpart,
                                           const float* __restrict__ W,
                                           const float* __restrict__ bias,
                                           float* __restrict__ out) {
    __shared__ float Msh[256];
    __shared__ float csh[16];
    __shared__ float Vsh[256];
    __shared__ float w0sh[16];
    const int tid = threadIdx.x;
    const int b = blockIdx.y;
    const int f = blockIdx.x * 128 + (tid & 127);
    const int jh = tid >> 7;

    {
        float m = 0.f;
#pragma unroll
        for (int p = 0; p < NSEG; ++p) m += Mpart[((size_t)p * 32 + b) * 256 + tid];
        Msh[tid] = m;
        if (tid < 16) {
            float c = 0.f;
#pragma unroll
            for (int p = 0; p < NSEG; ++p) c += cpart[((size_t)p * 32 + b) * 16 + tid];
            csh[tid] = c;
        }
    }
    __syncthreads();
    {
        const int s = tid >> 4, j = tid & 15;
        float acc = 0.f;
#pragma unroll
        for (int t = 0; t < 16; ++t) acc += Msh[s * 16 + t] * W[j * 32 + t];
        Vsh[s * 16 + j] = acc + W[j * 32 + 16 + s];
        if (s == 0) {
            float w0 = 0.f;
#pragma unroll
            for (int t = 0; t < 16; ++t) w0 += csh[t] * W[j * 32 + t];
            w0sh[j] = bias[j] - w0;
        }
    }
    __syncthreads();

    float As[16];
#pragma unroll
    for (int s = 0; s < 16; ++s)
        As[s] = data[(size_t)(b * 16 + s) * 2048 + f];
#pragma unroll
    for (int jj = 0; jj < 8; ++jj) {
        const int j = jh * 8 + jj;
        float p = w0sh[j];
#pragma unroll
        for (int s = 0; s < 16; ++s) p += As[s] * Vsh[s * 16 + j];
        float e = __builtin_amdgcn_exp2f(-LOG2E * p);
        float gate = __builtin_amdgcn_rcpf(1.0f + e);
        size_t r = (size_t)(j * 32 + b) * 2048 + f;
        out[r] = gate * data[r];
    }
}

extern "C" void kernel_launch(void* const* d_in, const int* in_sizes, int n_in,
                              void* d_out, int out_size, void* d_ws, size_t ws_size,
                              hipStream_t stream) {
    const float* data = (const float*)d_in[0];
    const float* attn = (const float*)d_in[1];
    const float* W    = (const float*)d_in[2];
    const float* bias = (const float*)d_in[3];
    float* out = (float*)d_out;
    float* ws  = (float*)d_ws;

    // big layout (floats): Lpart[4][32][2048] | Mpart[16][32][256] |
    //                      cpart[16][32][16]  | Afrag(4MB) | Tfrag(4MB)
    const size_t LP = 4 * 32 * 2048;              // 262144
    const size_t MP = NSEG * 32 * 256;            // 131072
    const size_t CP = NSEG * 32 * 16;             // 8192
    const size_t AF = 1048576;                    // 4MB as floats
    const size_t TF = 1048576;
    const size_t need_big = LP + MP + CP + AF + TF;

    if (ws_size >= need_big * sizeof(float)) {
        float* Lpart = ws;
        float* Mpart = ws + LP;
        float* cpart = Mpart + MP;
        _Float16* Afrag = (_Float16*)(cpart + CP);
        _Float16* Tfrag = (_Float16*)(cpart + CP + AF);
        kPrep<<<dim3(8, 32), 256, 0, stream>>>(data, attn, Afrag, Tfrag);
        kA<false><<<dim3(2048, 1, 1), 256, 0, stream>>>(Afrag, Tfrag, Lpart);
        kTail<<<dim3(16, 32), 256, 0, stream>>>(attn, Lpart, 4, Mpart, cpart);
        kC2<<<dim3(16, 32), 256, 0, stream>>>(data, Mpart, cpart, W, bias, out);
    } else {
        float* Lsum  = ws;            // 65536
        float* Mpart = ws + 65536;
        float* cpart = Mpart + MP;
        hipMemsetAsync(Lsum, 0, 65536 * sizeof(float), stream);
        kA_lds<<<dim3(2048, 1, 1), 256, 0, stream>>>(data, attn, Lsum);
        kTail<<<dim3(16, 32), 256, 0, stream>>>(attn, Lsum, 1, Mpart, cpart);
        kC2<<<dim3(16, 32), 256, 0, stream>>>(data, Mpart, cpart, W, bias, out);
    }
}